// Round 5
// baseline (391.029 us; speedup 1.0000x reference)
//
#include <hip/hip_runtime.h>
#include <stdint.h>

// Problem constants (match reference)
#define SLAB 8192    // SL
#define SUNL 16384   // SU
#define DIMX 1024
#define HID1 2048
#define HID2 512
#define KTRIES 8
#define MTOT (SLAB + SUNL)   // 24576

typedef __attribute__((ext_vector_type(8))) short bf16x8;    // 8 bf16 = 4 VGPRs
typedef __attribute__((ext_vector_type(4))) float f32x4;
typedef __attribute__((ext_vector_type(16))) float f32x16;

// fp32 -> bf16 round-to-nearest-even
__device__ __forceinline__ unsigned short f2bf(float f) {
  union { float f; uint32_t u; } c; c.f = f;
  return (unsigned short)((c.u + 0x7fffu + ((c.u >> 16) & 1u)) >> 16);
}

// async global->LDS, 16B per lane; lds dest = wave-uniform base + lane*16
__device__ __forceinline__ void async16(const void* g, void* l) {
  __builtin_amdgcn_global_load_lds(
      (const __attribute__((address_space(1))) unsigned int*)g,
      (__attribute__((address_space(3))) unsigned int*)l,
      16, 0, 0);
}

// ---------------------------------------------------------------------------
// Threefry2x32 (JAX-compatible, 20 rounds)
// ---------------------------------------------------------------------------
struct U2 { uint32_t x, y; };

__device__ __forceinline__ U2 threefry(uint32_t k0, uint32_t k1, uint32_t x0, uint32_t x1) {
  uint32_t ks2 = k0 ^ k1 ^ 0x1BD11BDAu;
  x0 += k0; x1 += k1;
#define TF_R(r) { x0 += x1; x1 = (x1 << (r)) | (x1 >> (32 - (r))); x1 ^= x0; }
  TF_R(13) TF_R(15) TF_R(26) TF_R(6)
  x0 += k1; x1 += ks2 + 1u;
  TF_R(17) TF_R(29) TF_R(16) TF_R(24)
  x0 += ks2; x1 += k0 + 2u;
  TF_R(13) TF_R(15) TF_R(26) TF_R(6)
  x0 += k0; x1 += k1 + 3u;
  TF_R(17) TF_R(29) TF_R(16) TF_R(24)
  x0 += k1; x1 += ks2 + 4u;
  TF_R(13) TF_R(15) TF_R(26) TF_R(6)
  x0 += ks2; x1 += k0 + 5u;
#undef TF_R
  return {x0, x1};
}

// ---------------------------------------------------------------------------
// prep_kernel: one launch for cast(X_l|X_u), transpose-cast W1, W2, and pairs.
// Block-id ranges select the role. All 256-thread blocks.
// ---------------------------------------------------------------------------
#define XL_BLOCKS (SLAB * DIMX / 4 / 256)           // 8192
#define CAST_BLOCKS (MTOT * DIMX / 4 / 256)         // 24576
#define T1_NBX (HID1 / 32)                          // 64
#define T1_BLOCKS ((HID1 / 32) * (DIMX / 32))       // 2048
#define T2_NBX (HID2 / 32)                          // 16
#define T2_BLOCKS ((HID2 / 32) * (HID1 / 32))       // 1024
#define PAIR_BLOCKS (SUNL / 256)                    // 64
#define PREP_BLOCKS (CAST_BLOCKS + T1_BLOCKS + T2_BLOCKS + PAIR_BLOCKS)

__global__ __launch_bounds__(256) void prep_kernel(
    const float* __restrict__ Xl, const float* __restrict__ Xu,
    const float* __restrict__ W1, const float* __restrict__ W2,
    const float* __restrict__ y_l, const float* __restrict__ y_u,
    unsigned short* __restrict__ X_bf, unsigned short* __restrict__ W1T,
    unsigned short* __restrict__ W2T,
    int* __restrict__ ia, int* __restrict__ ib, float* __restrict__ kv)
{
  __shared__ float t[32][33];
  int b = blockIdx.x;
  int tid = threadIdx.x;

  if (b < CAST_BLOCKS) {
    // ---- cast fp32 -> bf16, X = [Xl | Xu]
    const float* src; size_t i, doff;
    if (b < XL_BLOCKS) { src = Xl; i = (size_t)b * 256 + tid; doff = 0; }
    else { src = Xu; i = (size_t)(b - XL_BLOCKS) * 256 + tid; doff = (size_t)SLAB * DIMX / 4; }
    float4 v = ((const float4*)src)[i];
    ushort4 o;
    o.x = f2bf(v.x); o.y = f2bf(v.y); o.z = f2bf(v.z); o.w = f2bf(v.w);
    ((ushort4*)X_bf)[doff + i] = o;
  } else if (b < CAST_BLOCKS + T1_BLOCKS + T2_BLOCKS) {
    // ---- transpose + cast W[K][N] -> WT[N][K]
    const float* W; unsigned short* WT; int K, N, bx, by;
    if (b < CAST_BLOCKS + T1_BLOCKS) {
      int tb = b - CAST_BLOCKS;
      W = W1; WT = W1T; K = DIMX; N = HID1; bx = tb % T1_NBX; by = tb / T1_NBX;
    } else {
      int tb = b - CAST_BLOCKS - T1_BLOCKS;
      W = W2; WT = W2T; K = HID1; N = HID2; bx = tb % T2_NBX; by = tb / T2_NBX;
    }
    int k0 = by * 32, n0 = bx * 32;
    int tx = tid & 31, ty = tid >> 5;
#pragma unroll
    for (int i = 0; i < 32; i += 8)
      t[ty + i][tx] = W[(size_t)(k0 + ty + i) * N + n0 + tx];
    __syncthreads();
#pragma unroll
    for (int i = 0; i < 32; i += 8)
      WT[(size_t)(n0 + ty + i) * K + k0 + tx] = f2bf(t[tx][ty + i]);
  } else {
    // ---- pair sampling (verified R1: partitionable threefry, bits1^bits2, &8191)
    int r = (b - CAST_BLOCKS - T1_BLOCKS - T2_BLOCKS) * 256 + tid;
    U2 ka  = threefry(0u, 42u, 0u, 0u);
    U2 kb  = threefry(0u, 42u, 0u, 1u);
    U2 k2a = threefry(ka.x, ka.y, 0u, 1u);
    U2 k2b = threefry(kb.x, kb.y, 0u, 1u);
    int iav[KTRIES], ibv[KTRIES];
#pragma unroll
    for (int c = 0; c < KTRIES; ++c) {
      uint32_t tt = (uint32_t)(r * KTRIES + c);
      U2 oa = threefry(k2a.x, k2a.y, 0u, tt);
      U2 ob = threefry(k2b.x, k2b.y, 0u, tt);
      iav[c] = (int)((oa.x ^ oa.y) & (SLAB - 1));
      ibv[c] = (int)((ob.x ^ ob.y) & (SLAB - 1));
    }
    int a = iav[0], bb2 = ibv[0];
#pragma unroll
    for (int c = 0; c < KTRIES; ++c) {
      if (iav[c] != ibv[c] && y_l[iav[c]] != y_l[ibv[c]]) { a = iav[c]; bb2 = ibv[c]; break; }
    }
    float ya = y_l[a], yb = y_l[bb2];
    ia[r] = a; ib[r] = bb2; kv[r] = (y_u[r] - yb) / (ya - yb);
  }
}

// ---------------------------------------------------------------------------
// bf16 MFMA GEMM: C[M][N] = act(A[M][K] @ Bt[N][K]^T + bias)
// 128x128 tile, BK=32, 4 waves (2x2), each wave 64x64 via 2x2 of 32x32x16 MFMA.
//
// LDS swizzle (R3-verified, 0 conflicts): row r's four 16B k-chunks rotated by
// (r>>1)&3; fetched pre-rotated, un-rotated at fragment read.
// 32x32x16 A/B frag: lane l -> row/col = l&31, k = (l>>5)*8 + 0..7 (per ksub).
// C/D: col = lane&31, row = (reg&3) + 8*(reg>>2) + 4*(lane>>5)  [m74/m101].
//
// L2 swizzle: GROUP_M=8 m-panels per linear group so each XCD reuses one
// A-panel across n-blocks (cuts A re-fetch ~4x).
// Output rows [0,Msplit) -> C0, rest -> C1 (tile-aligned split).
// ---------------------------------------------------------------------------
#define GROUP_M 8

template<int OUT_BF16, int RELU>
__global__ __launch_bounds__(256) void gemm_bt_mfma(
    const unsigned short* __restrict__ A,   // [M][K] bf16
    const unsigned short* __restrict__ Bt,  // [N][K] bf16
    const float* __restrict__ bias,         // [N] fp32
    void* __restrict__ C0, void* __restrict__ C1, int Msplit,
    int M, int N, int K)
{
  __shared__ unsigned short As[128 * 32];   // 8 KB
  __shared__ unsigned short Bs[128 * 32];   // 8 KB

  const int tid  = threadIdx.x;
  const int wave = tid >> 6;
  const int lane = tid & 63;

  // L2 block swizzle (both layers: (M/128) % GROUP_M == 0, grid exact)
  const int nbx = N / 128;
  const int gsize = nbx * GROUP_M;
  const int grp = blockIdx.x / gsize, within = blockIdx.x % gsize;
  const int m0 = (grp * GROUP_M + (within % GROUP_M)) * 128;
  const int n0 = (within / GROUP_M) * 128;

  const int wm = (wave >> 1) * 64;
  const int wn = (wave & 1) * 64;

  // staging: lane covers row (wave*32 + lane/4), physical chunk slot (lane&3)
  const int srow  = wave * 32 + (lane >> 2);
  const int gchunk = ((lane & 3) - (srow >> 1)) & 3;   // rotation at fetch side
  const unsigned short* gA = A  + (size_t)(m0 + srow) * K + gchunk * 8;
  const unsigned short* gB = Bt + (size_t)(n0 + srow) * K + gchunk * 8;
  unsigned short* lA = As + wave * 32 * 32;            // wave-uniform LDS base
  unsigned short* lB = Bs + wave * 32 * 32;

  const int r31 = lane & 31;
  const int cHalf = lane >> 5;       // k-sub-chunk within each 16-k half

  f32x16 acc[2][2] = {};

  for (int k0 = 0; k0 < K; k0 += 32) {
    async16(gA + k0,                  lA);
    async16(gA + k0 + (size_t)16 * K, lA + 16 * 32);
    async16(gB + k0,                  lB);
    async16(gB + k0 + (size_t)16 * K, lB + 16 * 32);
    __syncthreads();

    bf16x8 ar[2][2], br[2][2];
#pragma unroll
    for (int i = 0; i < 2; ++i) {
      int rowA = wm + i * 32 + r31;
      int rowB = wn + i * 32 + r31;
#pragma unroll
      for (int kk = 0; kk < 2; ++kk) {
        int c = kk * 2 + cHalf;                        // logical 8-elem chunk
        ar[i][kk] = *(const bf16x8*)(As + rowA * 32 + ((c + (rowA >> 1)) & 3) * 8);
        br[i][kk] = *(const bf16x8*)(Bs + rowB * 32 + ((c + (rowB >> 1)) & 3) * 8);
      }
    }
#pragma unroll
    for (int kk = 0; kk < 2; ++kk)
#pragma unroll
      for (int i = 0; i < 2; ++i)
#pragma unroll
        for (int j = 0; j < 2; ++j)
          acc[i][j] = __builtin_amdgcn_mfma_f32_32x32x16_bf16(ar[i][kk], br[j][kk], acc[i][j], 0, 0, 0);
    __syncthreads();
  }

  // epilogue: bias + optional relu; per-block output select (tile-aligned)
  void* Cb = (m0 < Msplit) ? C0 : C1;
  const int mbase = ((m0 < Msplit) ? m0 : (m0 - Msplit)) + wm;
  const int ccolBase = n0 + wn + (lane & 31);
  const int crowHi = (lane >> 5) * 4;
#pragma unroll
  for (int j = 0; j < 2; ++j) {
    float bv = bias[ccolBase + j * 32];
#pragma unroll
    for (int i = 0; i < 2; ++i) {
#pragma unroll
      for (int reg = 0; reg < 16; ++reg) {
        int row = (reg & 3) + 8 * (reg >> 2) + crowHi;
        float v = acc[i][j][reg] + bv;
        if (RELU) v = fmaxf(v, 0.0f);
        size_t idx = (size_t)(mbase + i * 32 + row) * N + ccolBase + j * 32;
        if (OUT_BF16) ((unsigned short*)Cb)[idx] = f2bf(v);
        else          ((float*)Cb)[idx] = v;
      }
    }
  }
}

// ---------------------------------------------------------------------------
// post_kernel: comb (blocks [0, SUNL/2)) + yhat (blocks [SUNL/2, +SLAB/4))
// ---------------------------------------------------------------------------
#define COMB_BLOCKS (SUNL / 2)              // 8192
#define YHAT_BLOCKS (SLAB / 4)              // 2048
#define POST_BLOCKS (COMB_BLOCKS + YHAT_BLOCKS)

__global__ __launch_bounds__(256) void post_kernel(
    const float* __restrict__ feat_l, const float* __restrict__ W3,
    const float* __restrict__ b3, const int* __restrict__ ia,
    const int* __restrict__ ib, const float* __restrict__ kv,
    float* __restrict__ out_comb, float* __restrict__ out_yhat)
{
  int b = blockIdx.x;
  if (b < COMB_BLOCKS) {
    int row = b * 2 + (threadIdx.x >> 7);
    int c = (threadIdx.x & 127) << 2;
    float k = kv[row];
    float km1 = 1.0f - k;
    float4 fa = *(const float4*)(feat_l + (size_t)ia[row] * HID2 + c);
    float4 fb = *(const float4*)(feat_l + (size_t)ib[row] * HID2 + c);
    float4 o;
    o.x = k * fa.x + km1 * fb.x;
    o.y = k * fa.y + km1 * fb.y;
    o.z = k * fa.z + km1 * fb.z;
    o.w = k * fa.w + km1 * fb.w;
    *(float4*)(out_comb + (size_t)row * HID2 + c) = o;
  } else {
    int wave = threadIdx.x >> 6;
    int lane = threadIdx.x & 63;
    int row = (b - COMB_BLOCKS) * 4 + wave;
    const float* f = feat_l + (size_t)row * HID2;
    float s = 0.f;
#pragma unroll
    for (int j = 0; j < HID2 / 64; ++j) s = fmaf(f[lane + j * 64], W3[lane + j * 64], s);
#pragma unroll
    for (int off = 32; off; off >>= 1) s += __shfl_down(s, off);
    if (lane == 0) out_yhat[row] = s + b3[0];
  }
}

// ---------------------------------------------------------------------------
extern "C" void kernel_launch(void* const* d_in, const int* in_sizes, int n_in,
                              void* d_out, int out_size, void* d_ws, size_t ws_size,
                              hipStream_t stream)
{
  const float* X_l = (const float*)d_in[0];
  const float* y_l = (const float*)d_in[1];
  const float* X_u = (const float*)d_in[2];
  const float* y_u = (const float*)d_in[3];
  const float* W1  = (const float*)d_in[4];
  const float* b1  = (const float*)d_in[5];
  const float* W2  = (const float*)d_in[6];
  const float* b2  = (const float*)d_in[7];
  const float* W3  = (const float*)d_in[8];
  const float* b3  = (const float*)d_in[9];

  float* out_featu = (float*)d_out;
  float* out_comb  = out_featu + (size_t)SUNL * HID2;
  float* out_yhat  = out_comb + (size_t)SUNL * HID2;

  // Workspace (~174 MB): X_bf = [Xl|Xu] contig, H_bf = [Hl|Hu] contig
  unsigned short* X_bf  = (unsigned short*)d_ws;                 // [24576][1024]
  unsigned short* W1T   = X_bf + (size_t)MTOT * DIMX;
  unsigned short* W2T   = W1T + (size_t)HID1 * DIMX;
  unsigned short* H_bf  = W2T + (size_t)HID2 * HID1;             // [24576][2048]
  float* feat_l = (float*)(H_bf + (size_t)MTOT * HID1);
  int*   ai = (int*)(feat_l + (size_t)SLAB * HID2);
  int*   bi = ai + SUNL;
  float* kv = (float*)(bi + SUNL);

  dim3 blk(256);

  prep_kernel<<<dim3(PREP_BLOCKS), blk, 0, stream>>>(
      X_l, X_u, W1, W2, y_l, y_u, X_bf, W1T, W2T, ai, bi, kv);

  // layer 1 (merged l+u): H = relu(X @ W1 + b1) -> bf16  [3072 blocks]
  gemm_bt_mfma<1, 1><<<dim3((HID1 / 128) * (MTOT / 128)), blk, 0, stream>>>(
      X_bf, W1T, b1, H_bf, H_bf, MTOT * 2 /*no split*/, MTOT, HID1, DIMX);

  // layer 2 (merged l+u): feat = relu(H @ W2 + b2) -> fp32, split dest [768 blocks]
  gemm_bt_mfma<0, 1><<<dim3((HID2 / 128) * (MTOT / 128)), blk, 0, stream>>>(
      H_bf, W2T, b2, feat_l, out_featu, SLAB, MTOT, HID2, HID1);

  post_kernel<<<dim3(POST_BLOCKS), blk, 0, stream>>>(
      feat_l, W3, b3, ai, bi, kv, out_comb, out_yhat);
}

// Round 6
// 383.835 us; speedup vs baseline: 1.0187x; 1.0187x over previous
//
#include <hip/hip_runtime.h>
#include <stdint.h>

// Problem constants (match reference)
#define SLAB 8192    // SL
#define SUNL 16384   // SU
#define DIMX 1024
#define HID1 2048
#define HID2 512
#define KTRIES 8
#define MTOT (SLAB + SUNL)   // 24576

typedef __attribute__((ext_vector_type(8))) short bf16x8;    // 8 bf16 = 4 VGPRs
typedef __attribute__((ext_vector_type(4))) float f32x4;

// fp32 -> bf16 round-to-nearest-even
__device__ __forceinline__ unsigned short f2bf(float f) {
  union { float f; uint32_t u; } c; c.f = f;
  return (unsigned short)((c.u + 0x7fffu + ((c.u >> 16) & 1u)) >> 16);
}

// async global->LDS, 16B per lane; lds dest = wave-uniform base + lane*16
__device__ __forceinline__ void async16(const void* g, void* l) {
  __builtin_amdgcn_global_load_lds(
      (const __attribute__((address_space(1))) unsigned int*)g,
      (__attribute__((address_space(3))) unsigned int*)l,
      16, 0, 0);
}

// ---------------------------------------------------------------------------
// Threefry2x32 (JAX-compatible, 20 rounds)
// ---------------------------------------------------------------------------
struct U2 { uint32_t x, y; };

__device__ __forceinline__ U2 threefry(uint32_t k0, uint32_t k1, uint32_t x0, uint32_t x1) {
  uint32_t ks2 = k0 ^ k1 ^ 0x1BD11BDAu;
  x0 += k0; x1 += k1;
#define TF_R(r) { x0 += x1; x1 = (x1 << (r)) | (x1 >> (32 - (r))); x1 ^= x0; }
  TF_R(13) TF_R(15) TF_R(26) TF_R(6)
  x0 += k1; x1 += ks2 + 1u;
  TF_R(17) TF_R(29) TF_R(16) TF_R(24)
  x0 += ks2; x1 += k0 + 2u;
  TF_R(13) TF_R(15) TF_R(26) TF_R(6)
  x0 += k0; x1 += k1 + 3u;
  TF_R(17) TF_R(29) TF_R(16) TF_R(24)
  x0 += k1; x1 += ks2 + 4u;
  TF_R(13) TF_R(15) TF_R(26) TF_R(6)
  x0 += ks2; x1 += k0 + 5u;
#undef TF_R
  return {x0, x1};
}

// ---------------------------------------------------------------------------
// prep_kernel: one launch for cast(X_l|X_u), transpose-cast W1, W2, and pairs.
// ---------------------------------------------------------------------------
#define XL_BLOCKS (SLAB * DIMX / 4 / 256)           // 8192
#define CAST_BLOCKS (MTOT * DIMX / 4 / 256)         // 24576
#define T1_NBX (HID1 / 32)                          // 64
#define T1_BLOCKS ((HID1 / 32) * (DIMX / 32))       // 2048
#define T2_NBX (HID2 / 32)                          // 16
#define T2_BLOCKS ((HID2 / 32) * (HID1 / 32))       // 1024
#define PAIR_BLOCKS (SUNL / 256)                    // 64
#define PREP_BLOCKS (CAST_BLOCKS + T1_BLOCKS + T2_BLOCKS + PAIR_BLOCKS)

__global__ __launch_bounds__(256) void prep_kernel(
    const float* __restrict__ Xl, const float* __restrict__ Xu,
    const float* __restrict__ W1, const float* __restrict__ W2,
    const float* __restrict__ y_l, const float* __restrict__ y_u,
    unsigned short* __restrict__ X_bf, unsigned short* __restrict__ W1T,
    unsigned short* __restrict__ W2T,
    int* __restrict__ ia, int* __restrict__ ib, float* __restrict__ kv)
{
  __shared__ float t[32][33];
  int b = blockIdx.x;
  int tid = threadIdx.x;

  if (b < CAST_BLOCKS) {
    const float* src; size_t i, doff;
    if (b < XL_BLOCKS) { src = Xl; i = (size_t)b * 256 + tid; doff = 0; }
    else { src = Xu; i = (size_t)(b - XL_BLOCKS) * 256 + tid; doff = (size_t)SLAB * DIMX / 4; }
    float4 v = ((const float4*)src)[i];
    ushort4 o;
    o.x = f2bf(v.x); o.y = f2bf(v.y); o.z = f2bf(v.z); o.w = f2bf(v.w);
    ((ushort4*)X_bf)[doff + i] = o;
  } else if (b < CAST_BLOCKS + T1_BLOCKS + T2_BLOCKS) {
    const float* W; unsigned short* WT; int K, N, bx, by;
    if (b < CAST_BLOCKS + T1_BLOCKS) {
      int tb = b - CAST_BLOCKS;
      W = W1; WT = W1T; K = DIMX; N = HID1; bx = tb % T1_NBX; by = tb / T1_NBX;
    } else {
      int tb = b - CAST_BLOCKS - T1_BLOCKS;
      W = W2; WT = W2T; K = HID1; N = HID2; bx = tb % T2_NBX; by = tb / T2_NBX;
    }
    int k0 = by * 32, n0 = bx * 32;
    int tx = tid & 31, ty = tid >> 5;
#pragma unroll
    for (int i = 0; i < 32; i += 8)
      t[ty + i][tx] = W[(size_t)(k0 + ty + i) * N + n0 + tx];
    __syncthreads();
#pragma unroll
    for (int i = 0; i < 32; i += 8)
      WT[(size_t)(n0 + ty + i) * K + k0 + tx] = f2bf(t[tx][ty + i]);
  } else {
    // pair sampling (verified R1: partitionable threefry, bits1^bits2, &8191)
    int r = (b - CAST_BLOCKS - T1_BLOCKS - T2_BLOCKS) * 256 + tid;
    U2 ka  = threefry(0u, 42u, 0u, 0u);
    U2 kb  = threefry(0u, 42u, 0u, 1u);
    U2 k2a = threefry(ka.x, ka.y, 0u, 1u);
    U2 k2b = threefry(kb.x, kb.y, 0u, 1u);
    int iav[KTRIES], ibv[KTRIES];
#pragma unroll
    for (int c = 0; c < KTRIES; ++c) {
      uint32_t tt = (uint32_t)(r * KTRIES + c);
      U2 oa = threefry(k2a.x, k2a.y, 0u, tt);
      U2 ob = threefry(k2b.x, k2b.y, 0u, tt);
      iav[c] = (int)((oa.x ^ oa.y) & (SLAB - 1));
      ibv[c] = (int)((ob.x ^ ob.y) & (SLAB - 1));
    }
    int a = iav[0], bb2 = ibv[0];
#pragma unroll
    for (int c = 0; c < KTRIES; ++c) {
      if (iav[c] != ibv[c] && y_l[iav[c]] != y_l[ibv[c]]) { a = iav[c]; bb2 = ibv[c]; break; }
    }
    float ya = y_l[a], yb = y_l[bb2];
    ia[r] = a; ib[r] = bb2; kv[r] = (y_u[r] - yb) / (ya - yb);
  }
}

// ---------------------------------------------------------------------------
// bf16 MFMA GEMM: C[M][N] = act(A[M][K] @ Bt[N][K]^T + bias)
// 128x128 tile, BK=64, 4 waves (2x2), each wave 64x64 = 4x4 of 16x16x32 MFMA
// (R3-verified fragment scheme), 2 k-steps per LDS tile.
//
// LDS row = 64 elem = 128 B = exactly 32 banks, so row index does not offset
// banks. Swizzle: row r's 8 16B-chunks rotated by r&7 (logical chunk c at
// physical slot (c+r)&7). Staging fetches pre-rotated:
//   gchunk = ((lane&7) - (lane>>3)) & 7   (call-invariant: +8-row steps = 0 mod 8)
// Read: quarter-wave (fixed q,s) spans 16 rows -> slots cycle 8 values x2
//   -> 2 lanes/bank-group = free (m136).
//
// L2 swizzle: GROUP_M=8 (R4-verified: FETCH 204->123 MB).
// Output rows [0,Msplit) -> C0, rest -> C1 (tile-aligned split).
// ---------------------------------------------------------------------------
#define GROUP_M 8

template<int OUT_BF16, int RELU>
__global__ __launch_bounds__(256) void gemm_bt_mfma(
    const unsigned short* __restrict__ A,   // [M][K] bf16
    const unsigned short* __restrict__ Bt,  // [N][K] bf16
    const float* __restrict__ bias,         // [N] fp32
    void* __restrict__ C0, void* __restrict__ C1, int Msplit,
    int M, int N, int K)
{
  __shared__ unsigned short As[128 * 64];   // 16 KB
  __shared__ unsigned short Bs[128 * 64];   // 16 KB

  const int tid  = threadIdx.x;
  const int wave = tid >> 6;
  const int lane = tid & 63;

  // L2 block swizzle
  const int nbx = N / 128;
  const int gsize = nbx * GROUP_M;
  const int grp = blockIdx.x / gsize, within = blockIdx.x % gsize;
  const int m0 = (grp * GROUP_M + (within % GROUP_M)) * 128;
  const int n0 = (within / GROUP_M) * 128;

  const int wm = (wave >> 1) * 64;
  const int wn = (wave & 1) * 64;

  // staging: per call, 64 lanes x 16B = 8 rows of 128B; 4 calls cover the
  // wave's 32 rows. lane -> row (lane>>3), physical slot (lane&7).
  const int srow = wave * 32 + (lane >> 3);
  const int gchunk = ((lane & 7) - (lane >> 3)) & 7;
  const unsigned short* gA = A  + (size_t)(m0 + srow) * K + gchunk * 8;
  const unsigned short* gB = Bt + (size_t)(n0 + srow) * K + gchunk * 8;
  unsigned short* lA = As + wave * 32 * 64;
  unsigned short* lB = Bs + wave * 32 * 64;

  const int fr = lane & 15;          // fragment row/col within 16-tile
  const int q  = lane >> 4;          // k-group (k = q*8 + 0..7)

  f32x4 acc[4][4] = {};

  for (int k0 = 0; k0 < K; k0 += 64) {
#pragma unroll
    for (int c = 0; c < 4; ++c) {
      async16(gA + k0 + (size_t)(c * 8) * K, lA + c * 8 * 64);
      async16(gB + k0 + (size_t)(c * 8) * K, lB + c * 8 * 64);
    }
    __syncthreads();

#pragma unroll
    for (int s = 0; s < 2; ++s) {
      bf16x8 ar[4], br[4];
#pragma unroll
      for (int i = 0; i < 4; ++i) {
        int rowA = wm + i * 16 + fr;
        int rowB = wn + i * 16 + fr;
        int slotA = ((s * 4 + q + rowA) & 7) * 8;   // un-rotate
        int slotB = ((s * 4 + q + rowB) & 7) * 8;
        ar[i] = *(const bf16x8*)(As + rowA * 64 + slotA);
        br[i] = *(const bf16x8*)(Bs + rowB * 64 + slotB);
      }
#pragma unroll
      for (int i = 0; i < 4; ++i)
#pragma unroll
        for (int j = 0; j < 4; ++j)
          acc[i][j] = __builtin_amdgcn_mfma_f32_16x16x32_bf16(ar[i], br[j], acc[i][j], 0, 0, 0);
    }
    __syncthreads();
  }

  // epilogue: bias + optional relu; per-block output select (tile-aligned)
  // C/D layout: col = lane&15, row = (lane>>4)*4 + reg   [m89/m91 verified]
  void* Cb = (m0 < Msplit) ? C0 : C1;
  const int mbase = (m0 < Msplit) ? m0 : (m0 - Msplit);
  const int crow = mbase + wm + (lane >> 4) * 4;
  const int ccol = n0 + wn + (lane & 15);
#pragma unroll
  for (int j = 0; j < 4; ++j) {
    float bv = bias[ccol + j * 16];
#pragma unroll
    for (int i = 0; i < 4; ++i) {
#pragma unroll
      for (int r = 0; r < 4; ++r) {
        float v = acc[i][j][r] + bv;
        if (RELU) v = fmaxf(v, 0.0f);
        size_t idx = (size_t)(crow + i * 16 + r) * N + ccol + j * 16;
        if (OUT_BF16) ((unsigned short*)Cb)[idx] = f2bf(v);
        else          ((float*)Cb)[idx] = v;
      }
    }
  }
}

// ---------------------------------------------------------------------------
// post_kernel: comb (blocks [0, SUNL/2)) + yhat (blocks [SUNL/2, +SLAB/4))
// ---------------------------------------------------------------------------
#define COMB_BLOCKS (SUNL / 2)              // 8192
#define YHAT_BLOCKS (SLAB / 4)              // 2048
#define POST_BLOCKS (COMB_BLOCKS + YHAT_BLOCKS)

__global__ __launch_bounds__(256) void post_kernel(
    const float* __restrict__ feat_l, const float* __restrict__ W3,
    const float* __restrict__ b3, const int* __restrict__ ia,
    const int* __restrict__ ib, const float* __restrict__ kv,
    float* __restrict__ out_comb, float* __restrict__ out_yhat)
{
  int b = blockIdx.x;
  if (b < COMB_BLOCKS) {
    int row = b * 2 + (threadIdx.x >> 7);
    int c = (threadIdx.x & 127) << 2;
    float k = kv[row];
    float km1 = 1.0f - k;
    float4 fa = *(const float4*)(feat_l + (size_t)ia[row] * HID2 + c);
    float4 fb = *(const float4*)(feat_l + (size_t)ib[row] * HID2 + c);
    float4 o;
    o.x = k * fa.x + km1 * fb.x;
    o.y = k * fa.y + km1 * fb.y;
    o.z = k * fa.z + km1 * fb.z;
    o.w = k * fa.w + km1 * fb.w;
    *(float4*)(out_comb + (size_t)row * HID2 + c) = o;
  } else {
    int wave = threadIdx.x >> 6;
    int lane = threadIdx.x & 63;
    int row = (b - COMB_BLOCKS) * 4 + wave;
    const float* f = feat_l + (size_t)row * HID2;
    float s = 0.f;
#pragma unroll
    for (int j = 0; j < HID2 / 64; ++j) s = fmaf(f[lane + j * 64], W3[lane + j * 64], s);
#pragma unroll
    for (int off = 32; off; off >>= 1) s += __shfl_down(s, off);
    if (lane == 0) out_yhat[row] = s + b3[0];
  }
}

// ---------------------------------------------------------------------------
extern "C" void kernel_launch(void* const* d_in, const int* in_sizes, int n_in,
                              void* d_out, int out_size, void* d_ws, size_t ws_size,
                              hipStream_t stream)
{
  const float* X_l = (const float*)d_in[0];
  const float* y_l = (const float*)d_in[1];
  const float* X_u = (const float*)d_in[2];
  const float* y_u = (const float*)d_in[3];
  const float* W1  = (const float*)d_in[4];
  const float* b1  = (const float*)d_in[5];
  const float* W2  = (const float*)d_in[6];
  const float* b2  = (const float*)d_in[7];
  const float* W3  = (const float*)d_in[8];
  const float* b3  = (const float*)d_in[9];

  float* out_featu = (float*)d_out;
  float* out_comb  = out_featu + (size_t)SUNL * HID2;
  float* out_yhat  = out_comb + (size_t)SUNL * HID2;

  // Workspace (~174 MB): X_bf = [Xl|Xu] contig, H_bf = [Hl|Hu] contig
  unsigned short* X_bf  = (unsigned short*)d_ws;                 // [24576][1024]
  unsigned short* W1T   = X_bf + (size_t)MTOT * DIMX;
  unsigned short* W2T   = W1T + (size_t)HID1 * DIMX;
  unsigned short* H_bf  = W2T + (size_t)HID2 * HID1;             // [24576][2048]
  float* feat_l = (float*)(H_bf + (size_t)MTOT * HID1);
  int*   ai = (int*)(feat_l + (size_t)SLAB * HID2);
  int*   bi = ai + SUNL;
  float* kv = (float*)(bi + SUNL);

  dim3 blk(256);

  prep_kernel<<<dim3(PREP_BLOCKS), blk, 0, stream>>>(
      X_l, X_u, W1, W2, y_l, y_u, X_bf, W1T, W2T, ai, bi, kv);

  // layer 1 (merged l+u): H = relu(X @ W1 + b1) -> bf16  [3072 blocks]
  gemm_bt_mfma<1, 1><<<dim3((HID1 / 128) * (MTOT / 128)), blk, 0, stream>>>(
      X_bf, W1T, b1, H_bf, H_bf, MTOT * 2 /*no split*/, MTOT, HID1, DIMX);

  // layer 2 (merged l+u): feat = relu(H @ W2 + b2) -> fp32, split dest [768 blocks]
  gemm_bt_mfma<0, 1><<<dim3((HID2 / 128) * (MTOT / 128)), blk, 0, stream>>>(
      H_bf, W2T, b2, feat_l, out_featu, SLAB, MTOT, HID2, HID1);

  post_kernel<<<dim3(POST_BLOCKS), blk, 0, stream>>>(
      feat_l, W3, b3, ai, bi, kv, out_comb, out_yhat);
}